// Round 15
// baseline (89.633 us; speedup 1.0000x reference)
//
#include <hip/hip_runtime.h>

#define GAMMA 0.1f
#define ETA   0.3f

typedef __attribute__((ext_vector_type(8))) short short8;
typedef __attribute__((ext_vector_type(4))) float f32x4;

__device__ __forceinline__ short f2bf(float x) {
    // round-to-nearest-even fp32 -> bf16 payload (R2/R10/R13-proven)
    unsigned u = __float_as_uint(x);
    u += 0x7FFFu + ((u >> 16) & 1u);
    return (short)(u >> 16);
}

// R14 body (85.1us, PASS) with ONE scheduling lever: BOTH chunks' input
// loads are issued at the very top of the kernel, BEFORE the LDS staging +
// wfrag setup (~800cy) — the setup hides the ~900cy HBM latency that
// previously sat exposed after the barrier in every chunk (compiler cannot
// hoist loads across __syncthreads). +4 VGPR only; chunks manually unrolled
// with static selects (no runtime-indexed arrays). Everything else R14:
// LDS weights (typed scalar indexing), b2 via C-init, f2bf, NT stores,
// launch_bounds(256,6), ITERS=2 equivalent.
__global__ __launch_bounds__(256, 6) void market_impact_mfma(
    const float* __restrict__ os_g, const float* __restrict__ liq_g,
    const float* __restrict__ W1,  const float* __restrict__ b1g,
    const float* __restrict__ W2,  const float* __restrict__ b2,
    const float* __restrict__ lnw, const float* __restrict__ lnb,
    float* __restrict__ out, int B)
{
    __shared__ __align__(16) float s_uf[64], s_vf[64], s_bf[64];
    __shared__ __align__(16) float s_b2f[32], s_lwf[32], s_lbf[32];

    const int tid  = threadIdx.x;
    const int lane = tid & 63;
    const int g    = lane >> 4;   // k-group (0..3)
    const int c    = lane & 15;   // A row = out col (16-block); B col = data row

    // ---- FIRST: issue both chunks' input loads (hidden under setup) ----
    const long long wid = (long long)blockIdx.x * 4 + (tid >> 6);
    const long long base0 = wid * 128;            // 2 chunks x 64 rows
    const int r0 = (int)base0 + lane;
    const int r1 = r0 + 64;
    const bool ok0 = (base0 + lane) < (long long)B;
    const bool ok1 = (base0 + 64 + lane) < (long long)B;
    float o0v = ok0 ? os_g[r0]  : 0.f;
    float l0v = ok0 ? liq_g[r0] : 1.f;
    float o1v = ok1 ? os_g[r1]  : 0.f;
    float l1v = ok1 ? liq_g[r1] : 1.f;

    // ---- setup: stage weights to LDS (typed scalar stores, R13-proven) ----
    if (tid < 64) {
        float w2r = W1[128 + tid];
        s_uf[tid] = W1[tid]      + w2r;   // u[k] = W1[0][k] + W1[2][k]
        s_vf[tid] = W1[64 + tid] + w2r;   // v[k] = W1[1][k] + W1[2][k]
        s_bf[tid] = b1g[tid];
    } else if (tid < 96) {
        s_b2f[tid - 64] = b2[tid - 64];
    } else if (tid < 128) {
        s_lwf[tid - 96] = lnw[tid - 96];
    } else if (tid < 160) {
        s_lbf[tid - 128] = lnb[tid - 128];
    }

    // W2^T fragments (A-operand, bf16, 16 VGPR)
    short8 wfrag[2][2];
    #pragma unroll
    for (int kc = 0; kc < 2; ++kc)
        #pragma unroll
        for (int cc = 0; cc < 2; ++cc) {
            short8 t;
            #pragma unroll
            for (int j = 0; j < 8; ++j) {
                int k = kc * 32 + g * 8 + j;
                t[j] = f2bf(W2[k * 32 + cc * 16 + c]);
            }
            wfrag[kc][cc] = t;
        }

    __syncthreads();

    float* enc = out + 3LL * B;

    #pragma unroll
    for (int it = 0; it < 2; ++it) {
        long long base = base0 + it * 64;
        if (base >= B) break;                      // wave-uniform

        int r   = (it == 0) ? r0  : r1;
        bool ok = (it == 0) ? ok0 : ok1;
        float o  = (it == 0) ? o0v : o1v;          // static selects (full unroll)
        float lq = (it == 0) ? l0v : l1v;

        float perm = GAMMA * o / lq;               // exact
        float temp = ETA * copysignf(sqrtf(fabsf(o)), o) * rsqrtf(lq);
        float tot  = perm + temp;
        if (ok) {
            __builtin_nontemporal_store(perm, &out[r]);
            __builtin_nontemporal_store(temp, &out[B + r]);
            __builtin_nontemporal_store(tot,  &out[2 * B + r]);
        }

        #pragma unroll
        for (int mt = 0; mt < 4; ++mt) {
            float pm = __shfl(perm, mt * 16 + c);
            float tm = __shfl(temp, mt * 16 + c);

            // C-init = b2 (typed scalar LDS reads; exact fp32 bias)
            f32x4 d0 = { s_b2f[g * 4 + 0], s_b2f[g * 4 + 1],
                         s_b2f[g * 4 + 2], s_b2f[g * 4 + 3] };
            f32x4 d1 = { s_b2f[16 + g * 4 + 0], s_b2f[16 + g * 4 + 1],
                         s_b2f[16 + g * 4 + 2], s_b2f[16 + g * 4 + 3] };

            // kc=0: build a0, consume immediately
            {
                short8 a0;
                #pragma unroll
                for (int j = 0; j < 8; ++j) {
                    int k = g * 8 + j;
                    a0[j] = f2bf(fmaxf(0.f,
                              fmaf(pm, s_uf[k], fmaf(tm, s_vf[k], s_bf[k]))));
                }
                d0 = __builtin_amdgcn_mfma_f32_16x16x32_bf16(wfrag[0][0], a0, d0, 0, 0, 0);
                d1 = __builtin_amdgcn_mfma_f32_16x16x32_bf16(wfrag[0][1], a0, d1, 0, 0, 0);
            }
            // kc=1
            {
                short8 a1;
                #pragma unroll
                for (int j = 0; j < 8; ++j) {
                    int k = 32 + g * 8 + j;
                    a1[j] = f2bf(fmaxf(0.f,
                              fmaf(pm, s_uf[k], fmaf(tm, s_vf[k], s_bf[k]))));
                }
                d0 = __builtin_amdgcn_mfma_f32_16x16x32_bf16(wfrag[1][0], a1, d0, 0, 0, 0);
                d1 = __builtin_amdgcn_mfma_f32_16x16x32_bf16(wfrag[1][1], a1, d1, 0, 0, 0);
            }

            // LN over 32 cols: lane holds row (base+mt*16+c), cols cc*16+g*4+reg
            float s = 0.f, q = 0.f;
            #pragma unroll
            for (int reg = 0; reg < 4; ++reg) {
                s += d0[reg];  q = fmaf(d0[reg], d0[reg], q);
                s += d1[reg];  q = fmaf(d1[reg], d1[reg], q);
            }
            s += __shfl_xor(s, 16); s += __shfl_xor(s, 32);
            q += __shfl_xor(q, 16); q += __shfl_xor(q, 32);
            float mu   = s * 0.03125f;
            float var  = fmaf(q, 0.03125f, -mu * mu);
            float rstd = rsqrtf(var + 1e-5f);

            int row = (int)base + mt * 16 + c;
            if (row < B) {
                f32x4 o0, o1;
                #pragma unroll
                for (int reg = 0; reg < 4; ++reg) {
                    o0[reg] = fmaf((d0[reg] - mu) * rstd,
                                   s_lwf[g * 4 + reg],      s_lbf[g * 4 + reg]);
                    o1[reg] = fmaf((d1[reg] - mu) * rstd,
                                   s_lwf[16 + g * 4 + reg], s_lbf[16 + g * 4 + reg]);
                }
                float* rp = enc + (long long)row * 32;
                __builtin_nontemporal_store(o0, reinterpret_cast<f32x4*>(rp + g * 4));
                __builtin_nontemporal_store(o1, reinterpret_cast<f32x4*>(rp + 16 + g * 4));
            }
        }
    }
}

extern "C" void kernel_launch(void* const* d_in, const int* in_sizes, int n_in,
                              void* d_out, int out_size, void* d_ws, size_t ws_size,
                              hipStream_t stream) {
    const float* os_g = (const float*)d_in[0];
    const float* liq  = (const float*)d_in[1];
    const float* W1   = (const float*)d_in[2];
    const float* b1   = (const float*)d_in[3];
    const float* W2   = (const float*)d_in[4];
    const float* b2   = (const float*)d_in[5];
    const float* lnw  = (const float*)d_in[6];
    const float* lnb  = (const float*)d_in[7];
    float* out = (float*)d_out;
    const int B = in_sizes[0];

    const int rows_per_block = 512;   // 4 waves * 2 chunks * 64 rows
    const int grid = (B + rows_per_block - 1) / rows_per_block;   // 3907 @ B=2M
    market_impact_mfma<<<grid, 256, 0, stream>>>(
        os_g, liq, W1, b1, W2, b2, lnw, lnb, out, B);
}

// Round 16
// 86.364 us; speedup vs baseline: 1.0379x; 1.0379x over previous
//
#include <hip/hip_runtime.h>
#include <hip/hip_bf16.h>

#define GAMMA 0.1f
#define ETA   0.3f
#define ITERS 2   // 64-row chunks per wave — R2/R10 schedule (best: 84.9 us)

typedef __attribute__((ext_vector_type(8))) short short8;
typedef __attribute__((ext_vector_type(4))) float f32x4;

__device__ __forceinline__ short f2bf(float x) {
    // round-to-nearest-even fp32 -> bf16 payload (proven: absmax 1.56e-2)
    unsigned u = __float_as_uint(x);
    u += 0x7FFFu + ((u >> 16) & 1u);
    return (short)(u >> 16);
}

// FINAL: R10 verbatim — the session's best (84.9 us, PASS, absmax 0.0156).
// Structure: wave handles 2x64 rows; per chunk, lane l computes
// perm/temp/total for row base+l (coalesced NT stream stores), then 4
// m-tiles of 16 rows through MFMA with SWAPPED operands (d = mfma(W2^T, h))
// so lane&15 = output ROW -> LN reduces with xor16+xor32 only.
// h = relu(perm*u + temp*v + b1), u=W1[0]+W1[2], v=W1[1]+W1[2] (feats rank-2).
// Weights REGISTER-resident (LDS variant measured -5%: 144 ds_read/chunk).
// NT stores (+1%, only measured-positive lever). ~116 VGPR, 4 waves/SIMD.
// Plateau evidence: 85+-1 us reproduced 3x; all 9 variants (VALU cuts,
// occupancy 4->6, prefetch/hoist, ITERS 4/8, C-init) regressed or tied.
__global__ __launch_bounds__(256) void market_impact_mfma(
    const float* __restrict__ os_g, const float* __restrict__ liq_g,
    const float* __restrict__ W1,  const float* __restrict__ b1g,
    const float* __restrict__ W2,  const float* __restrict__ b2,
    const float* __restrict__ lnw, const float* __restrict__ lnb,
    float* __restrict__ out, int B)
{
    const int tid  = threadIdx.x;
    const int lane = tid & 63;
    const int g    = lane >> 4;   // k-group (0..3)
    const int c    = lane & 15;   // A row = out col (16-block); B col = data row

    // ---- one-time per-lane weights (registers) ----
    float u[16], v[16], bb[16];
    #pragma unroll
    for (int kc = 0; kc < 2; ++kc)
        #pragma unroll
        for (int j = 0; j < 8; ++j) {
            int k = kc * 32 + g * 8 + j;
            float w0 = W1[k], w1 = W1[64 + k], w2r = W1[128 + k];
            u[kc * 8 + j]  = w0 + w2r;
            v[kc * 8 + j]  = w1 + w2r;
            bb[kc * 8 + j] = b1g[k];
        }

    // W2^T fragments (A-operand): lane m=c is output col within block cc,
    // element j <-> k = kc*32 + g*8 + j.
    short8 wfrag[2][2];
    #pragma unroll
    for (int kc = 0; kc < 2; ++kc)
        #pragma unroll
        for (int cc = 0; cc < 2; ++cc) {
            short8 t;
            #pragma unroll
            for (int j = 0; j < 8; ++j) {
                int k = kc * 32 + g * 8 + j;
                t[j] = f2bf(W2[k * 32 + cc * 16 + c]);
            }
            wfrag[kc][cc] = t;
        }

    // epilogue constants: this lane's output cols are cc*16 + g*4 + reg
    float b2a[8], lnwa[8], lnba[8];
    #pragma unroll
    for (int cc = 0; cc < 2; ++cc) {
        float4 bq = *reinterpret_cast<const float4*>(b2  + cc * 16 + g * 4);
        float4 wq = *reinterpret_cast<const float4*>(lnw + cc * 16 + g * 4);
        float4 bl = *reinterpret_cast<const float4*>(lnb + cc * 16 + g * 4);
        b2a[cc*4+0] = bq.x; b2a[cc*4+1] = bq.y; b2a[cc*4+2] = bq.z; b2a[cc*4+3] = bq.w;
        lnwa[cc*4+0] = wq.x; lnwa[cc*4+1] = wq.y; lnwa[cc*4+2] = wq.z; lnwa[cc*4+3] = wq.w;
        lnba[cc*4+0] = bl.x; lnba[cc*4+1] = bl.y; lnba[cc*4+2] = bl.z; lnba[cc*4+3] = bl.w;
    }

    const long long wid = (long long)blockIdx.x * 4 + (tid >> 6);
    float* enc = out + 3LL * B;

    #pragma unroll 1
    for (int it = 0; it < ITERS; ++it) {
        long long base = (wid * ITERS + it) * 64;
        if (base >= B) break;                      // wave-uniform

        int r  = (int)base + lane;
        bool ok = r < B;
        float o  = ok ? os_g[r]  : 0.f;
        float lq = ok ? liq_g[r] : 1.f;
        float perm = GAMMA * o / lq;               // exact div
        float temp = ETA * copysignf(sqrtf(fabsf(o)), o) * rsqrtf(lq);
        float tot  = perm + temp;
        if (ok) {
            __builtin_nontemporal_store(perm, &out[r]);
            __builtin_nontemporal_store(temp, &out[B + r]);
            __builtin_nontemporal_store(tot,  &out[2 * B + r]);
        }

        #pragma unroll
        for (int mt = 0; mt < 4; ++mt) {
            // B-operand: h for row base + mt*16 + c, k = kc*32 + g*8 + j
            float pm = __shfl(perm, mt * 16 + c);
            float tm = __shfl(temp, mt * 16 + c);
            short8 a0, a1;
            #pragma unroll
            for (int j = 0; j < 8; ++j) {
                float h0 = fmaxf(0.f, fmaf(pm, u[j],     fmaf(tm, v[j],     bb[j])));
                float h1 = fmaxf(0.f, fmaf(pm, u[8 + j], fmaf(tm, v[8 + j], bb[8 + j])));
                a0[j] = f2bf(h0);
                a1[j] = f2bf(h1);
            }

            f32x4 d0 = {0.f, 0.f, 0.f, 0.f};
            f32x4 d1 = {0.f, 0.f, 0.f, 0.f};
            d0 = __builtin_amdgcn_mfma_f32_16x16x32_bf16(wfrag[0][0], a0, d0, 0, 0, 0);
            d0 = __builtin_amdgcn_mfma_f32_16x16x32_bf16(wfrag[1][0], a1, d0, 0, 0, 0);
            d1 = __builtin_amdgcn_mfma_f32_16x16x32_bf16(wfrag[0][1], a0, d1, 0, 0, 0);
            d1 = __builtin_amdgcn_mfma_f32_16x16x32_bf16(wfrag[1][1], a1, d1, 0, 0, 0);

            // x = d + b2 (epilogue); lane holds row (base+mt*16+c)
            float x[8];
            #pragma unroll
            for (int reg = 0; reg < 4; ++reg) {
                x[reg]     = d0[reg] + b2a[reg];
                x[4 + reg] = d1[reg] + b2a[4 + reg];
            }
            float s = 0.f, q = 0.f;
            #pragma unroll
            for (int j = 0; j < 8; ++j) { s += x[j]; q = fmaf(x[j], x[j], q); }
            s += __shfl_xor(s, 16); s += __shfl_xor(s, 32);
            q += __shfl_xor(q, 16); q += __shfl_xor(q, 32);
            float mu   = s * 0.03125f;
            float var  = fmaf(q, 0.03125f, -mu * mu);
            float rstd = rsqrtf(var + 1e-5f);

            int row = (int)base + mt * 16 + c;
            if (row < B) {
                f32x4 o0, o1;
                o0[0] = fmaf((x[0] - mu) * rstd, lnwa[0], lnba[0]);
                o0[1] = fmaf((x[1] - mu) * rstd, lnwa[1], lnba[1]);
                o0[2] = fmaf((x[2] - mu) * rstd, lnwa[2], lnba[2]);
                o0[3] = fmaf((x[3] - mu) * rstd, lnwa[3], lnba[3]);
                o1[0] = fmaf((x[4] - mu) * rstd, lnwa[4], lnba[4]);
                o1[1] = fmaf((x[5] - mu) * rstd, lnwa[5], lnba[5]);
                o1[2] = fmaf((x[6] - mu) * rstd, lnwa[6], lnba[6]);
                o1[3] = fmaf((x[7] - mu) * rstd, lnwa[7], lnba[7]);
                float* rp = enc + (long long)row * 32;
                __builtin_nontemporal_store(o0, reinterpret_cast<f32x4*>(rp + g * 4));
                __builtin_nontemporal_store(o1, reinterpret_cast<f32x4*>(rp + 16 + g * 4));
            }
        }
    }
}

extern "C" void kernel_launch(void* const* d_in, const int* in_sizes, int n_in,
                              void* d_out, int out_size, void* d_ws, size_t ws_size,
                              hipStream_t stream) {
    const float* os_g = (const float*)d_in[0];
    const float* liq  = (const float*)d_in[1];
    const float* W1   = (const float*)d_in[2];
    const float* b1   = (const float*)d_in[3];
    const float* W2   = (const float*)d_in[4];
    const float* b2   = (const float*)d_in[5];
    const float* lnw  = (const float*)d_in[6];
    const float* lnb  = (const float*)d_in[7];
    float* out = (float*)d_out;
    const int B = in_sizes[0];

    const int rows_per_block = 4 * ITERS * 64;   // 512
    const int grid = (B + rows_per_block - 1) / rows_per_block;   // 3907 @ B=2M
    market_impact_mfma<<<grid, 256, 0, stream>>>(
        os_g, liq, W1, b1, W2, b2, lnw, lnb, out, B);
}